// Round 3
// baseline (222.554 us; speedup 1.0000x reference)
//
#include <hip/hip_runtime.h>

#define B_ROWS 4096
#define N_CLUST 1024
#define KDIM 4096
#define NKT 32          // source k-tiles of 128 halfs
#define NSTEP 32        // pipeline k-steps per block (split-K half: 32 x BK=64)

#define EMA_OLD 0.01f
#define EMA_NEW 0.99f
#define MARGIN 2.0f     // screen d2 error max ~0.27 (40 sigma headroom)

typedef unsigned short ushortT;
typedef _Float16 half8 __attribute__((ext_vector_type(8)));
typedef float f32x16 __attribute__((ext_vector_type(16)));

// ---------------- workspace layout (bytes) ----------------
#define WS_WINNER_OFF 0                  // i32[1024], memset 0xFF
#define WS_Z_OFF      4096               // i32[4096]
#define WS_YY_OFF     20480              // f32[4096]
#define WS_MM_OFF     36864              // f32[1024]
#define WS_D2A_OFF    65536                       // f32[4096*1024] = 16 MiB
#define WS_D2B_OFF    (WS_D2A_OFF + 16777216)     // f32[4096*1024] = 16 MiB
#define WS_YHI_OFF    (WS_D2B_OFF + 16777216)     // 32 MB
#define WS_MHI_OFF    (WS_YHI_OFF + 33554432)     // 8 MB
#define WS_END        (WS_MHI_OFF + 8388608)      // ~74.8 MB

// ---------------- fused f16-hi convert + row sum-of-squares ----------------
// Tiled layout: block (rb, kt) of 64 rows x 128 halfs contiguous (16 KB).
// Within a row (16 chunks of 16B), logical chunk c stored at p = c ^ (r&15).
// One 256-thread block per source row; 512 chunks/row, 2 per thread.
__global__ __launch_bounds__(256) void convert_sumsq(
    const float* __restrict__ ysrc, const float* __restrict__ msrc,
    ushortT* __restrict__ yhi, ushortT* __restrict__ mhi,
    float* __restrict__ yy, float* __restrict__ mm) {
    const int blk = blockIdx.x;
    const float* src;
    ushortT* hi;
    float* out;
    int row;
    if (blk < B_ROWS) {
        src = ysrc; hi = yhi; out = yy + blk; row = blk;
    } else {
        row = blk - B_ROWS;
        src = msrc; hi = mhi; out = mm + row;
    }
    const int r = row & 63, rb = row >> 6;
    const int t = threadIdx.x;
    float s = 0.f;
#pragma unroll
    for (int h = 0; h < 2; ++h) {
        int ci = h * 256 + t;        // physical chunk in row [0,512)
        int kt = ci >> 4, p = ci & 15;
        int c = p ^ (r & 15);
        const float* sp = src + ((size_t)row << 12) + kt * 128 + c * 8;
        float4 v0 = *(const float4*)sp;
        float4 v1 = *(const float4*)(sp + 4);
        float vv[8] = {v0.x, v0.y, v0.z, v0.w, v1.x, v1.y, v1.z, v1.w};
        half8 hv;
#pragma unroll
        for (int i = 0; i < 8; ++i) {
            hv[i] = (_Float16)vv[i];
            s += vv[i] * vv[i];
        }
        size_t off = (((size_t)rb * NKT + kt) * 64 + r) * 128 + p * 8;
        *(half8*)(hi + off) = hv;
    }
    for (int off = 32; off > 0; off >>= 1) s += __shfl_down(s, off, 64);
    __shared__ float red[4];
    if ((t & 63) == 0) red[t >> 6] = s;
    __syncthreads();
    if (t == 0) out[0] = red[0] + red[1] + red[2] + red[3];
}

// ---------------- screen GEMM: d2_screen = yy - 2*Yhi@Mhi^T + mm ----------
__device__ __forceinline__ void gload_lds16(const void* g, void* l) {
    __builtin_amdgcn_global_load_lds(
        (const __attribute__((address_space(1))) unsigned int*)g,
        (__attribute__((address_space(3))) unsigned int*)l, 16, 0, 0);
}

// LDS tile: 128 rows x 64 halfs (128B/row); logical 8-half chunk c stored
// at p = c ^ (r&7). Source gather (per-lane global addr) realizes this from
// the source's p_src = c_src ^ (r&15) swizzle: p_src = p | ((ksel^bit3(r))<<3).
__device__ __forceinline__ half8 ldfrag64(const ushortT* s, int r, int c) {
    int p = c ^ (r & 7);
    return *(const half8*)(s + r * 64 + p * 8);
}

// v4: BK=64 double-buffered pipeline with counted vmcnt (T3+T4), 2 blocks/CU.
// 128x128 block tile, 4 waves each owning 64x64 (1 KB LDS per MFMA).
// LDS = 2 bufs x (16KB A + 16KB B) = 64 KB -> still 2 blocks/CU.
// Per step: issue 8 global_load_lds for step i+1, s_waitcnt vmcnt(8) (only
// step i's loads drained - prefetch stays in flight across the barrier),
// s_barrier, 16 ds_read_b128 + 16 MFMA per wave, s_barrier. The vmcnt(0)
// structural stall of v3's 2-phase loop is gone; HBM latency hides under
// compute + the co-resident block. setprio(1) around the MFMA cluster (T5:
// independent-block, counted-vmcnt regime).
// Per-k16 global accumulation order identical to v3 -> d2 bit-identical.
__global__ __launch_bounds__(256, 2) void screen_gemm(
    const ushortT* __restrict__ Ah, const ushortT* __restrict__ Bh,
    const float* __restrict__ yy, const float* __restrict__ mm,
    float* __restrict__ d2a, float* __restrict__ d2b) {
    __shared__ __align__(16) ushortT sA[2][128 * 64];   // 2 x 16 KB
    __shared__ __align__(16) ushortT sB[2][128 * 64];   // 2 x 16 KB

    const int t = threadIdx.x, w = t >> 6, l = t & 63;
    const int by = blockIdx.x & 7;            // col panel -> XCD pinned
    const int kh = (blockIdx.x >> 3) & 1;     // K half
    const int bx = blockIdx.x >> 4;           // row tile 0..31
    const int row0 = bx * 128, col0 = by * 128;
    const int wr = (w >> 1) * 64, wc = (w & 1) * 64;   // wave 64x64 tile
    const int m0 = l & 31, hsel = l >> 5;

    // per-lane source offset inside a (row-octet, 128B-half) gather chunk:
    // lane l covers row (l>>3) of the octet, 16B slot (l&7).
    const int laneoff = (l >> 3) * 256 + (l & 7) * 16;
    const char* gAbase = (const char*)Ah + laneoff;
    const char* gBbase = (const char*)Bh + laneoff;

    f32x16 acc[2][2];
#pragma unroll
    for (int i = 0; i < 2; ++i)
#pragma unroll
        for (int j = 0; j < 2; ++j)
#pragma unroll
            for (int r = 0; r < 16; ++r) acc[i][j][r] = 0.f;

    // Stage one BK=64 tile pair (A:16KB + B:16KB) = 32 chunks of 1KB,
    // 8 per wave. Chunk g in [0,16): rows g*8..g*8+7 of the 128-row tile.
    // tile sel = g>>3, r6 = (g&7)*8 + (l>>3), bit3(r) = (g&1)<<3.
#define STAGE(buf, kt2)                                                       \
    {                                                                         \
        const int kt_ = (kt2) >> 1, ks_ = (kt2) & 1;                          \
        _Pragma("unroll")                                                     \
        for (int j = 0; j < 4; ++j) {                                         \
            const int g = w * 4 + j;                                          \
            const int hi_ = (ks_ ^ (g & 1)) << 7;                             \
            size_t goA = ((size_t)((2 * bx + (g >> 3)) * NKT + kt_) << 14) +  \
                         (g & 7) * 2048 + hi_;                                \
            gload_lds16(gAbase + goA, (char*)&sA[buf][0] + g * 1024);         \
            size_t goB = ((size_t)((2 * by + (g >> 3)) * NKT + kt_) << 14) +  \
                         (g & 7) * 2048 + hi_;                                \
            gload_lds16(gBbase + goB, (char*)&sB[buf][0] + g * 1024);         \
        }                                                                     \
    }

    const int kt2_0 = kh * NSTEP;
    STAGE(0, kt2_0);                      // prologue: 8 loads in flight

    for (int i = 0; i < NSTEP; ++i) {
        const int buf = i & 1;
        if (i + 1 < NSTEP) {
            STAGE(buf ^ 1, kt2_0 + i + 1);                 // 16 in flight
            asm volatile("s_waitcnt vmcnt(8)" ::: "memory"); // drain step i only
        } else {
            asm volatile("s_waitcnt vmcnt(0)" ::: "memory");
        }
        __builtin_amdgcn_s_barrier();     // step i's tile visible to all waves

        const ushortT* tA = &sA[buf][0] + wr * 64;
        const ushortT* tB = &sB[buf][0] + wc * 64;
        __builtin_amdgcn_s_setprio(1);
#pragma unroll
        for (int kk = 0; kk < 4; ++kk) {
            int c = kk * 2 + hsel;
            half8 a0 = ldfrag64(tA, m0, c);
            half8 a1 = ldfrag64(tA, 32 + m0, c);
            half8 b0 = ldfrag64(tB, m0, c);
            half8 b1 = ldfrag64(tB, 32 + m0, c);
            acc[0][0] = __builtin_amdgcn_mfma_f32_32x32x16_f16(a0, b0, acc[0][0], 0, 0, 0);
            acc[0][1] = __builtin_amdgcn_mfma_f32_32x32x16_f16(a0, b1, acc[0][1], 0, 0, 0);
            acc[1][0] = __builtin_amdgcn_mfma_f32_32x32x16_f16(a1, b0, acc[1][0], 0, 0, 0);
            acc[1][1] = __builtin_amdgcn_mfma_f32_32x32x16_f16(a1, b1, acc[1][1], 0, 0, 0);
        }
        __builtin_amdgcn_s_setprio(0);
        asm volatile("" ::: "memory");    // keep ds_reads above the barrier
        __builtin_amdgcn_s_barrier();     // all reads of buf done before re-stage
    }
#undef STAGE

    if (kh == 0) {
#pragma unroll
        for (int i = 0; i < 2; ++i)
#pragma unroll
            for (int j = 0; j < 2; ++j) {
                const int gcol = col0 + wc + j * 32 + m0;
                const float mv = mm[gcol];
#pragma unroll
                for (int r = 0; r < 16; ++r) {
                    int ri = (r & 3) + 8 * (r >> 2) + 4 * hsel;
                    int grow = row0 + wr + i * 32 + ri;
                    d2a[(size_t)grow * N_CLUST + gcol] =
                        yy[grow] - 2.0f * acc[i][j][r] + mv;
                }
            }
    } else {
#pragma unroll
        for (int i = 0; i < 2; ++i)
#pragma unroll
            for (int j = 0; j < 2; ++j) {
                const int gcol = col0 + wc + j * 32 + m0;
#pragma unroll
                for (int r = 0; r < 16; ++r) {
                    int ri = (r & 3) + 8 * (r >> 2) + 4 * hsel;
                    int grow = row0 + wr + i * 32 + ri;
                    d2b[(size_t)grow * N_CLUST + gcol] = -2.0f * acc[i][j][r];
                }
            }
    }
}

// ---------------- rescreen: exact argmin per row ----------------
// One wave per row. Screen d2 = d2a + d2b (split-K partials). Candidates
// within MARGIN of the row min. 1 candidate -> it's the argmin. Else exact
// double-acc dots.
__global__ __launch_bounds__(256) void rescreen(
    const float* __restrict__ d2a, const float* __restrict__ d2b,
    const float* __restrict__ ysrc, const float* __restrict__ msrc,
    const float* __restrict__ yy, const float* __restrict__ mm,
    int* __restrict__ z) {
    const int row = blockIdx.x * 4 + (threadIdx.x >> 6);
    const int l = threadIdx.x & 63;
    const float* dra = d2a + (size_t)row * N_CLUST;
    const float* drb = d2b + (size_t)row * N_CLUST;

    float v[16];
#pragma unroll
    for (int k = 0; k < 16; ++k) v[k] = dra[l + 64 * k] + drb[l + 64 * k];

    float mn = v[0];
#pragma unroll
    for (int k = 1; k < 16; ++k) mn = fminf(mn, v[k]);
#pragma unroll
    for (int s = 1; s <= 32; s <<= 1) mn = fminf(mn, __shfl_xor(mn, s, 64));
    const float thr = mn + MARGIN;

    int cnt = 0;
#pragma unroll
    for (int k = 0; k < 16; ++k) cnt += (v[k] <= thr) ? 1 : 0;
#pragma unroll
    for (int s = 1; s <= 32; s <<= 1) cnt += __shfl_xor(cnt, s, 64);

    int zj;
    if (cnt == 1) {
        int cj = 0x7FFFFFFF;
#pragma unroll
        for (int k = 0; k < 16; ++k)
            if (v[k] <= thr) cj = min(cj, l + 64 * k);
#pragma unroll
        for (int s = 1; s <= 32; s <<= 1) cj = min(cj, __shfl_xor(cj, s, 64));
        zj = cj;
    } else {
        double bestd = 1e300;
        int bestj = -1;
        const float4* yp = (const float4*)(ysrc + (size_t)row * KDIM);
        for (int k = 0; k < 16; ++k) {
            unsigned long long mask = __ballot(v[k] <= thr);
            while (mask) {
                int lb = __ffsll((unsigned long long)mask) - 1;
                mask &= mask - 1;
                int j = 64 * k + lb;
                const float4* mp = (const float4*)(msrc + (size_t)j * KDIM);
                double acc = 0.0;
#pragma unroll
                for (int tt = 0; tt < 16; ++tt) {
                    float4 a = yp[l + 64 * tt];
                    float4 b = mp[l + 64 * tt];
                    acc += (double)a.x * b.x + (double)a.y * b.y +
                           (double)a.z * b.z + (double)a.w * b.w;
                }
#pragma unroll
                for (int s = 1; s <= 32; s <<= 1)
                    acc += __shfl_xor(acc, s, 64);
                double d2x = (double)yy[row] - 2.0 * acc + (double)mm[j];
                if (d2x < bestd) { bestd = d2x; bestj = j; }  // strict: low j wins ties
            }
        }
        zj = bestj;
    }
    if (l == 0) z[row] = zj;
}

// ---------------- scatter + output ----------------
__global__ void pick_winner(const int* __restrict__ z,
                            int* __restrict__ winner) {
    int b = blockIdx.x * blockDim.x + threadIdx.x;
    if (b < B_ROWS) atomicMax(&winner[z[b]], b);
}

__global__ __launch_bounds__(256) void write_out(
    const float* __restrict__ y, const float* __restrict__ m,
    const float* __restrict__ sd, const int* __restrict__ winner,
    float* __restrict__ out) {
    const int idx = blockIdx.x;
    const int t = threadIdx.x;
    const int w = winner[idx];
    const float4* mp = (const float4*)(m + (size_t)idx * KDIM);
    const float4* sp = (const float4*)(sd + (size_t)idx * KDIM);
    float4* om = (float4*)(out + (size_t)idx * KDIM);
    float4* os = (float4*)(out + (size_t)(N_CLUST + idx) * KDIM);
    if (w >= 0) {
        const float4* yp = (const float4*)(y + (size_t)w * KDIM);
        for (int i = t; i < KDIM / 4; i += 256) {
            float4 mv = mp[i], yv = yp[i], sv = sp[i];
            float4 nm, ns;
            nm.x = mv.x * EMA_OLD + yv.x * EMA_NEW;
            nm.y = mv.y * EMA_OLD + yv.y * EMA_NEW;
            nm.z = mv.z * EMA_OLD + yv.z * EMA_NEW;
            nm.w = mv.w * EMA_OLD + yv.w * EMA_NEW;
            float dx = nm.x - yv.x, dy = nm.y - yv.y;
            float dz = nm.z - yv.z, dw = nm.w - yv.w;
            ns.x = dx * dx * EMA_OLD + sv.x * EMA_NEW;
            ns.y = dy * dy * EMA_OLD + sv.y * EMA_NEW;
            ns.z = dz * dz * EMA_OLD + sv.z * EMA_NEW;
            ns.w = dw * dw * EMA_OLD + sv.w * EMA_NEW;
            om[i] = nm;
            os[i] = ns;
        }
    } else {
        for (int i = t; i < KDIM / 4; i += 256) {
            om[i] = mp[i];
            os[i] = sp[i];
        }
    }
}

extern "C" void kernel_launch(void* const* d_in, const int* in_sizes, int n_in,
                              void* d_out, int out_size, void* d_ws,
                              size_t ws_size, hipStream_t stream) {
    const float* y  = (const float*)d_in[0];
    const float* m  = (const float*)d_in[1];
    const float* sd = (const float*)d_in[2];
    float* out = (float*)d_out;

    char* ws = (char*)d_ws;
    int* winner = (int*)(ws + WS_WINNER_OFF);
    int* z      = (int*)(ws + WS_Z_OFF);
    float* yy   = (float*)(ws + WS_YY_OFF);
    float* mm   = (float*)(ws + WS_MM_OFF);
    float* d2a  = (float*)(ws + WS_D2A_OFF);
    float* d2b  = (float*)(ws + WS_D2B_OFF);
    ushortT* yhi = (ushortT*)(ws + WS_YHI_OFF);
    ushortT* mhi = (ushortT*)(ws + WS_MHI_OFF);

    hipMemsetAsync(winner, 0xFF, 4096, stream);   // winner = -1

    convert_sumsq<<<B_ROWS + N_CLUST, 256, 0, stream>>>(y, m, yhi, mhi, yy, mm);

    screen_gemm<<<(B_ROWS / 128) * (N_CLUST / 128) * 2, 256, 0, stream>>>(
        yhi, mhi, yy, mm, d2a, d2b);

    rescreen<<<B_ROWS / 4, 256, 0, stream>>>(d2a, d2b, y, m, yy, mm, z);

    pick_winner<<<B_ROWS / 256, 256, 0, stream>>>(z, winner);
    write_out<<<N_CLUST, 256, 0, stream>>>(y, m, sd, winner, out);
}

// Round 4
// 217.686 us; speedup vs baseline: 1.0224x; 1.0224x over previous
//
#include <hip/hip_runtime.h>

#define B_ROWS 4096
#define N_CLUST 1024
#define KDIM 4096
#define NKT 32          // source k-tiles of 128 halfs
#define NSTEP 16        // BK=64 steps per block (split-K x4: 8 kt x 2)

#define EMA_OLD 0.01f
#define EMA_NEW 0.99f
#define MARGIN 2.0f     // screen error: ~0.27 f16 + 0.125 i16 quant << 2.0
#define PSCALE 16.0f    // i16 partial quantization scale

typedef unsigned short ushortT;
typedef _Float16 half8 __attribute__((ext_vector_type(8)));
typedef float f32x16 __attribute__((ext_vector_type(16)));

// ---------------- workspace layout (bytes) ----------------
#define WS_WINNER_OFF 0                  // i32[1024], memset 0xFF
#define WS_Z_OFF      4096               // (unused)
#define WS_YY_OFF     20480              // f32[4096]
#define WS_MM_OFF     36864              // f32[1024]
#define WS_P_OFF      65536              // i16[4][4096][1024] = 4 x 8 MiB
#define WS_YHI_OFF    (WS_P_OFF + 33554432)      // 33.6 MB
#define WS_MHI_OFF    (WS_YHI_OFF + 33554432)    // 8.4 MB
#define WS_END        (WS_MHI_OFF + 8388608)     // ~75 MB (same as proven)

// ---------------- fused f16-hi convert + row sum-of-squares ----------------
// Tiled layout: block (rb, kt) of 64 rows x 128 halfs contiguous (16 KB).
// Within a row (16 chunks of 16B), logical chunk c stored at p = c ^ (r&15).
__global__ __launch_bounds__(256) void convert_sumsq(
    const float* __restrict__ ysrc, const float* __restrict__ msrc,
    ushortT* __restrict__ yhi, ushortT* __restrict__ mhi,
    float* __restrict__ yy, float* __restrict__ mm) {
    const int blk = blockIdx.x;
    const float* src;
    ushortT* hi;
    float* out;
    int row;
    if (blk < B_ROWS) {
        src = ysrc; hi = yhi; out = yy + blk; row = blk;
    } else {
        row = blk - B_ROWS;
        src = msrc; hi = mhi; out = mm + row;
    }
    const int r = row & 63, rb = row >> 6;
    const int t = threadIdx.x;
    float s = 0.f;
#pragma unroll
    for (int h = 0; h < 2; ++h) {
        int ci = h * 256 + t;        // physical chunk in row [0,512)
        int kt = ci >> 4, p = ci & 15;
        int c = p ^ (r & 15);
        const float* sp = src + ((size_t)row << 12) + kt * 128 + c * 8;
        float4 v0 = *(const float4*)sp;
        float4 v1 = *(const float4*)(sp + 4);
        float vv[8] = {v0.x, v0.y, v0.z, v0.w, v1.x, v1.y, v1.z, v1.w};
        half8 hv;
#pragma unroll
        for (int i = 0; i < 8; ++i) {
            hv[i] = (_Float16)vv[i];
            s += vv[i] * vv[i];
        }
        size_t off = (((size_t)rb * NKT + kt) * 64 + r) * 128 + p * 8;
        *(half8*)(hi + off) = hv;
    }
    for (int off = 32; off > 0; off >>= 1) s += __shfl_down(s, off, 64);
    __shared__ float red[4];
    if ((t & 63) == 0) red[t >> 6] = s;
    __syncthreads();
    if (t == 0) out[0] = red[0] + red[1] + red[2] + red[3];
}

// ---------------- screen GEMM: partials of -2*Yhi@Mhi^T ------------------
__device__ __forceinline__ void gload_lds16(const void* g, void* l) {
    __builtin_amdgcn_global_load_lds(
        (const __attribute__((address_space(1))) unsigned int*)g,
        (__attribute__((address_space(3))) unsigned int*)l, 16, 0, 0);
}

// v5 LDS layout (BK=64, conflict-free): row-pair interleaved.
// phys_byte(r, c) = (r>>1)*256 + ((((r&1)<<3)|c) ^ ((r>>1)&15))*16.
// Among 32 lanes (r=0..31, c fixed) exactly 2 lanes share a 16B slot
// (q and q^8 with opposite r&1) -> 2-way = free (v3-class, measured 0).
__device__ __forceinline__ half8 ldfrag_pair(const ushortT* s, int r, int c) {
    int q = r >> 1;
    int sl = ((((r & 1) << 3) | c) ^ (q & 15));
    return *(const half8*)(s + q * 128 + sl * 8);
}

// v5: split-K x4 -> 1024 blocks = 4 blocks/CU (4 waves/SIMD TLP, v1's proven
// extraction mechanism) with v3's 1 KB/MFMA read traffic. 128x128 block tile,
// 4 waves each 64x64 (2x2 of 32x32). BK=64, single-buffered 32 KB LDS.
// Per step: stage 32 KB (8 gload/wave, linear dest + swizzled per-lane
// global source realizing the pair-interleave), sync, 16 ds_read + 16 MFMA.
// Output: per-K-quarter partial of -2*acc quantized to i16 at scale 16
// (4 x 8 MB fits the old d2a+d2b footprint; quant err 4/32 << MARGIN).
__global__ __launch_bounds__(256, 4) void screen_gemm(
    const ushortT* __restrict__ Ah, const ushortT* __restrict__ Bh,
    short* __restrict__ pws) {
    __shared__ __align__(16) ushortT sA[128 * 64];   // 16 KB
    __shared__ __align__(16) ushortT sB[128 * 64];   // 16 KB

    const int t = threadIdx.x, w = t >> 6, l = t & 63;
    const int by = blockIdx.x & 7;            // col panel -> XCD pinned
    const int kh = (blockIdx.x >> 3) & 3;     // K quarter
    const int bx = blockIdx.x >> 5;           // row tile 0..31
    const int row0 = bx * 128, col0 = by * 128;
    const int wr = (w >> 1) * 64, wc = (w & 1) * 64;   // wave 64x64 tile
    const int m0 = l & 31, hsel = l >> 5;

    // Per-lane source offsets for the 4 staged chunks (constant across steps;
    // ks flips byte bit 7). Chunk g covers LDS bytes [g*1024, g*1024+1024):
    // q = g*4 + (l>>4), sl = l&15 -> source (row r=2q+b, chunk c) with
    // u = sl ^ (q&15), b = u>>3, c = u&7; src chunk p_src = ((ks<<3)|c)^(R&15).
    int laneoff[4];
#pragma unroll
    for (int j = 0; j < 4; ++j) {
        int g = w * 4 + j;
        int q = g * 4 + (l >> 4);
        int u = (l & 15) ^ (q & 15);
        int rr = 2 * q + (u >> 3);
        int R = rr & 63;
        int hi3 = (R >> 3) & 1;
        laneoff[j] = R * 256 + ((((hi3 << 3) | ((u & 7) ^ (R & 7)))) << 4);
    }

    f32x16 acc[2][2];
#pragma unroll
    for (int i = 0; i < 2; ++i)
#pragma unroll
        for (int j = 0; j < 2; ++j)
#pragma unroll
            for (int r = 0; r < 16; ++r) acc[i][j][r] = 0.f;

    const int ra0 = wr + m0, ra1 = wr + 32 + m0;
    const int rb0 = wc + m0, rb1 = wc + 32 + m0;

#pragma unroll 2
    for (int i = 0; i < NSTEP; ++i) {
        const int kt_ = kh * (NKT / 4) + (i >> 1);
        const int ks_ = i & 1;
        __syncthreads();   // all waves done reading LDS from previous step
#pragma unroll
        for (int j = 0; j < 4; ++j) {
            const int g = w * 4 + j;
            const int lo = laneoff[j] ^ (ks_ << 7);
            const size_t tbA = ((size_t)((2 * bx + (g >> 3)) * NKT + kt_) << 14);
            const size_t tbB = ((size_t)((2 * by + (g >> 3)) * NKT + kt_) << 14);
            gload_lds16((const char*)Ah + tbA + lo, (char*)sA + g * 1024);
            gload_lds16((const char*)Bh + tbB + lo, (char*)sB + g * 1024);
        }
        __syncthreads();   // implicit vmcnt(0): staged tile visible

#pragma unroll
        for (int kk = 0; kk < 4; ++kk) {
            int c = kk * 2 + hsel;
            half8 a0 = ldfrag_pair(sA, ra0, c);
            half8 a1 = ldfrag_pair(sA, ra1, c);
            half8 b0 = ldfrag_pair(sB, rb0, c);
            half8 b1 = ldfrag_pair(sB, rb1, c);
            acc[0][0] = __builtin_amdgcn_mfma_f32_32x32x16_f16(a0, b0, acc[0][0], 0, 0, 0);
            acc[0][1] = __builtin_amdgcn_mfma_f32_32x32x16_f16(a0, b1, acc[0][1], 0, 0, 0);
            acc[1][0] = __builtin_amdgcn_mfma_f32_32x32x16_f16(a1, b0, acc[1][0], 0, 0, 0);
            acc[1][1] = __builtin_amdgcn_mfma_f32_32x32x16_f16(a1, b1, acc[1][1], 0, 0, 0);
        }
    }

    // Store i16 partial: round(-2*acc*16). |2 acc| <= ~16 sigma = 1024 << 2047.
    short* pk = pws + (size_t)kh * (B_ROWS * (size_t)N_CLUST);
#pragma unroll
    for (int i = 0; i < 2; ++i)
#pragma unroll
        for (int j = 0; j < 2; ++j) {
            const int gcol = col0 + wc + j * 32 + m0;
#pragma unroll
            for (int r = 0; r < 16; ++r) {
                int ri = (r & 3) + 8 * (r >> 2) + 4 * hsel;
                int grow = row0 + wr + i * 32 + ri;
                float q = fmaxf(fminf(acc[i][j][r] * (-2.0f * PSCALE),
                                      32767.f), -32767.f);
                pk[(size_t)grow * N_CLUST + gcol] = (short)__float2int_rn(q);
            }
        }
}

// ---------------- rescreen: exact argmin per row + winner scatter ---------
// One wave per row. d2_screen = yy[row] + mm[col] + (p0+p1+p2+p3)/16.
// Candidates within MARGIN of row min; 1 candidate -> done, else exact
// double-acc dots. Lane 0 does the pick_winner atomicMax (fused).
__global__ __launch_bounds__(256) void rescreen(
    const short* __restrict__ pws, const float* __restrict__ ysrc,
    const float* __restrict__ msrc, const float* __restrict__ yy,
    const float* __restrict__ mm, int* __restrict__ winner) {
    const int row = blockIdx.x * 4 + (threadIdx.x >> 6);
    const int l = threadIdx.x & 63;
    const size_t rb = (size_t)row * N_CLUST;
    const float yyr = yy[row];

    float v[16];
#pragma unroll
    for (int k = 0; k < 16; ++k) {
        int col = l + 64 * k;
        int s = (int)pws[rb + col];
        s += (int)pws[rb + col + (B_ROWS * (size_t)N_CLUST)];
        s += (int)pws[rb + col + 2 * (B_ROWS * (size_t)N_CLUST)];
        s += (int)pws[rb + col + 3 * (B_ROWS * (size_t)N_CLUST)];
        v[k] = yyr + mm[col] + (float)s * (1.0f / PSCALE);
    }

    float mn = v[0];
#pragma unroll
    for (int k = 1; k < 16; ++k) mn = fminf(mn, v[k]);
#pragma unroll
    for (int s = 1; s <= 32; s <<= 1) mn = fminf(mn, __shfl_xor(mn, s, 64));
    const float thr = mn + MARGIN;

    int cnt = 0;
#pragma unroll
    for (int k = 0; k < 16; ++k) cnt += (v[k] <= thr) ? 1 : 0;
#pragma unroll
    for (int s = 1; s <= 32; s <<= 1) cnt += __shfl_xor(cnt, s, 64);

    int zj;
    if (cnt == 1) {
        int cj = 0x7FFFFFFF;
#pragma unroll
        for (int k = 0; k < 16; ++k)
            if (v[k] <= thr) cj = min(cj, l + 64 * k);
#pragma unroll
        for (int s = 1; s <= 32; s <<= 1) cj = min(cj, __shfl_xor(cj, s, 64));
        zj = cj;
    } else {
        double bestd = 1e300;
        int bestj = -1;
        const float4* yp = (const float4*)(ysrc + (size_t)row * KDIM);
        for (int k = 0; k < 16; ++k) {
            unsigned long long mask = __ballot(v[k] <= thr);
            while (mask) {
                int lb = __ffsll((unsigned long long)mask) - 1;
                mask &= mask - 1;
                int j = 64 * k + lb;
                const float4* mp = (const float4*)(msrc + (size_t)j * KDIM);
                double acc = 0.0;
#pragma unroll
                for (int tt = 0; tt < 16; ++tt) {
                    float4 a = yp[l + 64 * tt];
                    float4 b = mp[l + 64 * tt];
                    acc += (double)a.x * b.x + (double)a.y * b.y +
                           (double)a.z * b.z + (double)a.w * b.w;
                }
#pragma unroll
                for (int s = 1; s <= 32; s <<= 1)
                    acc += __shfl_xor(acc, s, 64);
                double d2x = (double)yy[row] - 2.0 * acc + (double)mm[j];
                if (d2x < bestd) { bestd = d2x; bestj = j; }  // strict: low j wins ties
            }
        }
        zj = bestj;
    }
    if (l == 0) atomicMax(&winner[zj], row);   // fused pick_winner
}

// ---------------- output ----------------
__global__ __launch_bounds__(256) void write_out(
    const float* __restrict__ y, const float* __restrict__ m,
    const float* __restrict__ sd, const int* __restrict__ winner,
    float* __restrict__ out) {
    const int idx = blockIdx.x;
    const int t = threadIdx.x;
    const int w = winner[idx];
    const float4* mp = (const float4*)(m + (size_t)idx * KDIM);
    const float4* sp = (const float4*)(sd + (size_t)idx * KDIM);
    float4* om = (float4*)(out + (size_t)idx * KDIM);
    float4* os = (float4*)(out + (size_t)(N_CLUST + idx) * KDIM);
    if (w >= 0) {
        const float4* yp = (const float4*)(y + (size_t)w * KDIM);
        for (int i = t; i < KDIM / 4; i += 256) {
            float4 mv = mp[i], yv = yp[i], sv = sp[i];
            float4 nm, ns;
            nm.x = mv.x * EMA_OLD + yv.x * EMA_NEW;
            nm.y = mv.y * EMA_OLD + yv.y * EMA_NEW;
            nm.z = mv.z * EMA_OLD + yv.z * EMA_NEW;
            nm.w = mv.w * EMA_OLD + yv.w * EMA_NEW;
            float dx = nm.x - yv.x, dy = nm.y - yv.y;
            float dz = nm.z - yv.z, dw = nm.w - yv.w;
            ns.x = dx * dx * EMA_OLD + sv.x * EMA_NEW;
            ns.y = dy * dy * EMA_OLD + sv.y * EMA_NEW;
            ns.z = dz * dz * EMA_OLD + sv.z * EMA_NEW;
            ns.w = dw * dw * EMA_OLD + sv.w * EMA_NEW;
            om[i] = nm;
            os[i] = ns;
        }
    } else {
        for (int i = t; i < KDIM / 4; i += 256) {
            om[i] = mp[i];
            os[i] = sp[i];
        }
    }
}

extern "C" void kernel_launch(void* const* d_in, const int* in_sizes, int n_in,
                              void* d_out, int out_size, void* d_ws,
                              size_t ws_size, hipStream_t stream) {
    const float* y  = (const float*)d_in[0];
    const float* m  = (const float*)d_in[1];
    const float* sd = (const float*)d_in[2];
    float* out = (float*)d_out;

    char* ws = (char*)d_ws;
    int* winner = (int*)(ws + WS_WINNER_OFF);
    float* yy   = (float*)(ws + WS_YY_OFF);
    float* mm   = (float*)(ws + WS_MM_OFF);
    short* pws  = (short*)(ws + WS_P_OFF);
    ushortT* yhi = (ushortT*)(ws + WS_YHI_OFF);
    ushortT* mhi = (ushortT*)(ws + WS_MHI_OFF);

    hipMemsetAsync(winner, 0xFF, 4096, stream);   // winner = -1

    convert_sumsq<<<B_ROWS + N_CLUST, 256, 0, stream>>>(y, m, yhi, mhi, yy, mm);

    screen_gemm<<<(B_ROWS / 128) * (N_CLUST / 128) * 4, 256, 0, stream>>>(
        yhi, mhi, pws);

    rescreen<<<B_ROWS / 4, 256, 0, stream>>>(pws, y, m, yy, mm, winner);

    write_out<<<N_CLUST, 256, 0, stream>>>(y, m, sd, winner, out);
}

// Round 5
// 215.441 us; speedup vs baseline: 1.0330x; 1.0104x over previous
//
#include <hip/hip_runtime.h>

#define B_ROWS 4096
#define N_CLUST 1024
#define KDIM 4096
#define NKT 32          // source k-tiles of 128 halfs
#define NSTEP 16        // BK=64 steps per block (split-K x4: 8 kt x 2)

#define EMA_OLD 0.01f
#define EMA_NEW 0.99f
#define MARGIN 2.0f     // screen error: ~0.27 f16 + 0.125 i16 quant << 2.0
#define PSCALE 16.0f    // i16 partial quantization scale
#define PLANE ((size_t)B_ROWS * N_CLUST)

typedef unsigned short ushortT;
typedef _Float16 half8 __attribute__((ext_vector_type(8)));
typedef short short8v __attribute__((ext_vector_type(8)));
typedef float f32x16 __attribute__((ext_vector_type(16)));

// ---------------- workspace layout (bytes) ----------------
#define WS_WINNER_OFF 0                  // i32[1024], init by convert_sumsq
#define WS_YY_OFF     20480              // f32[4096]
#define WS_MM_OFF     36864              // f32[1024]
#define WS_P_OFF      65536              // i16[4][4096][1024] = 4 x 8 MiB
#define WS_YHI_OFF    (WS_P_OFF + 33554432)      // 33.6 MB
#define WS_MHI_OFF    (WS_YHI_OFF + 33554432)    // 8.4 MB
#define WS_END        (WS_MHI_OFF + 8388608)     // ~75 MB

// ---------------- fused f16-hi convert + row sum-of-squares ----------------
// Tiled layout: block (rb, kt) of 64 rows x 128 halfs contiguous (16 KB).
// Within a row (16 chunks of 16B), logical chunk c stored at p = c ^ (r&15).
// m-branch blocks also init winner[row] = -1 (replaces the memset node).
__global__ __launch_bounds__(256) void convert_sumsq(
    const float* __restrict__ ysrc, const float* __restrict__ msrc,
    ushortT* __restrict__ yhi, ushortT* __restrict__ mhi,
    float* __restrict__ yy, float* __restrict__ mm,
    int* __restrict__ winner) {
    const int blk = blockIdx.x;
    const float* src;
    ushortT* hi;
    float* out;
    int row;
    if (blk < B_ROWS) {
        src = ysrc; hi = yhi; out = yy + blk; row = blk;
    } else {
        row = blk - B_ROWS;
        src = msrc; hi = mhi; out = mm + row;
        if (threadIdx.x == 0) winner[row] = -1;   // fused memset
    }
    const int r = row & 63, rb = row >> 6;
    const int t = threadIdx.x;
    float s = 0.f;
#pragma unroll
    for (int h = 0; h < 2; ++h) {
        int ci = h * 256 + t;        // physical chunk in row [0,512)
        int kt = ci >> 4, p = ci & 15;
        int c = p ^ (r & 15);
        const float* sp = src + ((size_t)row << 12) + kt * 128 + c * 8;
        float4 v0 = *(const float4*)sp;
        float4 v1 = *(const float4*)(sp + 4);
        float vv[8] = {v0.x, v0.y, v0.z, v0.w, v1.x, v1.y, v1.z, v1.w};
        half8 hv;
#pragma unroll
        for (int i = 0; i < 8; ++i) {
            hv[i] = (_Float16)vv[i];
            s += vv[i] * vv[i];
        }
        size_t off = (((size_t)rb * NKT + kt) * 64 + r) * 128 + p * 8;
        *(half8*)(hi + off) = hv;
    }
    for (int off = 32; off > 0; off >>= 1) s += __shfl_down(s, off, 64);
    __shared__ float red[4];
    if ((t & 63) == 0) red[t >> 6] = s;
    __syncthreads();
    if (t == 0) out[0] = red[0] + red[1] + red[2] + red[3];
}

// ---------------- screen GEMM: partials of -2*Yhi@Mhi^T ------------------
__device__ __forceinline__ void gload_lds16(const void* g, void* l) {
    __builtin_amdgcn_global_load_lds(
        (const __attribute__((address_space(1))) unsigned int*)g,
        (__attribute__((address_space(3))) unsigned int*)l, 16, 0, 0);
}

// v5 LDS layout (BK=64, conflict-free): row-pair interleaved.
// phys_byte(r, c) = (r>>1)*256 + ((((r&1)<<3)|c) ^ ((r>>1)&15))*16.
// Among 32 lanes exactly 2 share a 16B slot -> 2-way = free (measured 0).
__device__ __forceinline__ half8 ldfrag_pair(const ushortT* s, int r, int c) {
    int q = r >> 1;
    int sl = ((((r & 1) << 3) | c) ^ (q & 15));
    return *(const half8*)(s + q * 128 + sl * 8);
}

// v5 structure (proven 48.4 us, conflicts 0): split-K x4 -> 1024 blocks =
// 4 blocks/CU. 128x128 block tile, 4 waves each 64x64. BK=64 single-buffered
// 32 KB LDS. Output: per-K-quarter partial of -2*acc as i16 at scale 16.
__global__ __launch_bounds__(256, 4) void screen_gemm(
    const ushortT* __restrict__ Ah, const ushortT* __restrict__ Bh,
    short* __restrict__ pws) {
    __shared__ __align__(16) ushortT sA[128 * 64];   // 16 KB
    __shared__ __align__(16) ushortT sB[128 * 64];   // 16 KB

    const int t = threadIdx.x, w = t >> 6, l = t & 63;
    const int by = blockIdx.x & 7;            // col panel -> XCD pinned
    const int kh = (blockIdx.x >> 3) & 3;     // K quarter
    const int bx = blockIdx.x >> 5;           // row tile 0..31
    const int row0 = bx * 128, col0 = by * 128;
    const int wr = (w >> 1) * 64, wc = (w & 1) * 64;   // wave 64x64 tile
    const int m0 = l & 31, hsel = l >> 5;

    // Per-lane source offsets for the 4 staged chunks (ks flips byte bit 7).
    int laneoff[4];
#pragma unroll
    for (int j = 0; j < 4; ++j) {
        int g = w * 4 + j;
        int q = g * 4 + (l >> 4);
        int u = (l & 15) ^ (q & 15);
        int rr = 2 * q + (u >> 3);
        int R = rr & 63;
        int hi3 = (R >> 3) & 1;
        laneoff[j] = R * 256 + ((((hi3 << 3) | ((u & 7) ^ (R & 7)))) << 4);
    }

    f32x16 acc[2][2];
#pragma unroll
    for (int i = 0; i < 2; ++i)
#pragma unroll
        for (int j = 0; j < 2; ++j)
#pragma unroll
            for (int r = 0; r < 16; ++r) acc[i][j][r] = 0.f;

    const int ra0 = wr + m0, ra1 = wr + 32 + m0;
    const int rb0 = wc + m0, rb1 = wc + 32 + m0;

#pragma unroll 2
    for (int i = 0; i < NSTEP; ++i) {
        const int kt_ = kh * (NKT / 4) + (i >> 1);
        const int ks_ = i & 1;
        __syncthreads();   // all waves done reading LDS from previous step
#pragma unroll
        for (int j = 0; j < 4; ++j) {
            const int g = w * 4 + j;
            const int lo = laneoff[j] ^ (ks_ << 7);
            const size_t tbA = ((size_t)((2 * bx + (g >> 3)) * NKT + kt_) << 14);
            const size_t tbB = ((size_t)((2 * by + (g >> 3)) * NKT + kt_) << 14);
            gload_lds16((const char*)Ah + tbA + lo, (char*)sA + g * 1024);
            gload_lds16((const char*)Bh + tbB + lo, (char*)sB + g * 1024);
        }
        __syncthreads();   // implicit vmcnt(0): staged tile visible

#pragma unroll
        for (int kk = 0; kk < 4; ++kk) {
            int c = kk * 2 + hsel;
            half8 a0 = ldfrag_pair(sA, ra0, c);
            half8 a1 = ldfrag_pair(sA, ra1, c);
            half8 b0 = ldfrag_pair(sB, rb0, c);
            half8 b1 = ldfrag_pair(sB, rb1, c);
            acc[0][0] = __builtin_amdgcn_mfma_f32_32x32x16_f16(a0, b0, acc[0][0], 0, 0, 0);
            acc[0][1] = __builtin_amdgcn_mfma_f32_32x32x16_f16(a0, b1, acc[0][1], 0, 0, 0);
            acc[1][0] = __builtin_amdgcn_mfma_f32_32x32x16_f16(a1, b0, acc[1][0], 0, 0, 0);
            acc[1][1] = __builtin_amdgcn_mfma_f32_32x32x16_f16(a1, b1, acc[1][1], 0, 0, 0);
        }
    }

    // Store i16 partial: round(-2*acc*16). |2 acc| <= ~16 sigma = 1024 << 2047.
    short* pk = pws + (size_t)kh * PLANE;
#pragma unroll
    for (int i = 0; i < 2; ++i)
#pragma unroll
        for (int j = 0; j < 2; ++j) {
            const int gcol = col0 + wc + j * 32 + m0;
#pragma unroll
            for (int r = 0; r < 16; ++r) {
                int ri = (r & 3) + 8 * (r >> 2) + 4 * hsel;
                int grow = row0 + wr + i * 32 + ri;
                float q = fmaxf(fminf(acc[i][j][r] * (-2.0f * PSCALE),
                                      32767.f), -32767.f);
                pk[(size_t)grow * N_CLUST + gcol] = (short)__float2int_rn(q);
            }
        }
}

// ---------------- rescreen: exact argmin per row + winner scatter ---------
// v6: vectorized. One wave per row; lane l owns cols [l*16, l*16+16).
// Loads: 4 planes x 2 short8 (16B) + 4 float4 mm = 13 VMEM/lane (was 80
// scalar). Per-lane (min1, argmin, min2), 6-step shfl_xor merge (col sets
// disjoint -> merge exact). Fast path: min2-min1 > MARGIN (yy constant per
// row, cancels). Rare exact path: fp64 dots, explicit lowest-j tiebreak.
__global__ __launch_bounds__(256) void rescreen(
    const short* __restrict__ pws, const float* __restrict__ ysrc,
    const float* __restrict__ msrc, const float* __restrict__ yy,
    const float* __restrict__ mm, int* __restrict__ winner) {
    const int row = blockIdx.x * 4 + (threadIdx.x >> 6);
    const int l = threadIdx.x & 63;
    const size_t rb = (size_t)row * N_CLUST;

    // gather 16-col strip summed over 4 planes
    int sacc[16];
#pragma unroll
    for (int q = 0; q < 16; ++q) sacc[q] = 0;
    const short* base = pws + rb + l * 16;
#pragma unroll
    for (int pl = 0; pl < 4; ++pl) {
        const short8v* sp = (const short8v*)(base + pl * PLANE);
        short8v x0 = sp[0], x1 = sp[1];
#pragma unroll
        for (int e = 0; e < 8; ++e) {
            sacc[e] += (int)x0[e];
            sacc[8 + e] += (int)x1[e];
        }
    }
    float v[16];
    const float4* mmv = (const float4*)(mm + l * 16);
#pragma unroll
    for (int h = 0; h < 4; ++h) {
        float4 mv = mmv[h];
        v[h * 4 + 0] = mv.x + (float)sacc[h * 4 + 0] * (1.0f / PSCALE);
        v[h * 4 + 1] = mv.y + (float)sacc[h * 4 + 1] * (1.0f / PSCALE);
        v[h * 4 + 2] = mv.z + (float)sacc[h * 4 + 2] * (1.0f / PSCALE);
        v[h * 4 + 3] = mv.w + (float)sacc[h * 4 + 3] * (1.0f / PSCALE);
    }

    // per-lane min1/argmin/min2 (ascending q: strict < keeps lowest col)
    float m1 = v[0], m2 = 3.0e38f;
    int a1 = l * 16;
#pragma unroll
    for (int q = 1; q < 16; ++q) {
        float x = v[q];
        if (x < m1) { m2 = m1; m1 = x; a1 = l * 16 + q; }
        else m2 = fminf(m2, x);
    }
    // cross-lane merge (disjoint col sets)
#pragma unroll
    for (int s = 1; s <= 32; s <<= 1) {
        float o1 = __shfl_xor(m1, s, 64);
        int ob = __shfl_xor(a1, s, 64);
        float o2 = __shfl_xor(m2, s, 64);
        if (o1 < m1 || (o1 == m1 && ob < a1)) {
            m2 = fminf(o2, m1); m1 = o1; a1 = ob;
        } else {
            m2 = fminf(m2, o1);
        }
    }

    int zj;
    if (m2 - m1 > MARGIN) {
        zj = a1;                      // unique screen winner
    } else {
        const float thr = m1 + MARGIN;
        double bestd = 1e300;
        int bestj = 0x7FFFFFFF;
        const float yyr = yy[row];
        const float4* yp = (const float4*)(ysrc + (size_t)row * KDIM);
        for (int q = 0; q < 16; ++q) {
            unsigned long long mask = __ballot(v[q] <= thr);
            while (mask) {
                int lb = __ffsll((unsigned long long)mask) - 1;
                mask &= mask - 1;
                int j = lb * 16 + q;
                const float4* mp = (const float4*)(msrc + (size_t)j * KDIM);
                double acc = 0.0;
#pragma unroll
                for (int tt = 0; tt < 16; ++tt) {
                    float4 a = yp[l + 64 * tt];
                    float4 b = mp[l + 64 * tt];
                    acc += (double)a.x * b.x + (double)a.y * b.y +
                           (double)a.z * b.z + (double)a.w * b.w;
                }
#pragma unroll
                for (int s = 1; s <= 32; s <<= 1)
                    acc += __shfl_xor(acc, s, 64);
                double d2x = (double)yyr - 2.0 * acc + (double)mm[j];
                if (d2x < bestd || (d2x == bestd && j < bestj)) {
                    bestd = d2x; bestj = j;   // lowest j wins ties
                }
            }
        }
        zj = bestj;
    }
    if (l == 0) atomicMax(&winner[zj], row);   // fused pick_winner
}

// ---------------- output ----------------
__global__ __launch_bounds__(256) void write_out(
    const float* __restrict__ y, const float* __restrict__ m,
    const float* __restrict__ sd, const int* __restrict__ winner,
    float* __restrict__ out) {
    const int idx = blockIdx.x;
    const int t = threadIdx.x;
    const int w = winner[idx];
    const float4* mp = (const float4*)(m + (size_t)idx * KDIM);
    const float4* sp = (const float4*)(sd + (size_t)idx * KDIM);
    float4* om = (float4*)(out + (size_t)idx * KDIM);
    float4* os = (float4*)(out + (size_t)(N_CLUST + idx) * KDIM);
    if (w >= 0) {
        const float4* yp = (const float4*)(y + (size_t)w * KDIM);
        for (int i = t; i < KDIM / 4; i += 256) {
            float4 mv = mp[i], yv = yp[i], sv = sp[i];
            float4 nm, ns;
            nm.x = mv.x * EMA_OLD + yv.x * EMA_NEW;
            nm.y = mv.y * EMA_OLD + yv.y * EMA_NEW;
            nm.z = mv.z * EMA_OLD + yv.z * EMA_NEW;
            nm.w = mv.w * EMA_OLD + yv.w * EMA_NEW;
            float dx = nm.x - yv.x, dy = nm.y - yv.y;
            float dz = nm.z - yv.z, dw = nm.w - yv.w;
            ns.x = dx * dx * EMA_OLD + sv.x * EMA_NEW;
            ns.y = dy * dy * EMA_OLD + sv.y * EMA_NEW;
            ns.z = dz * dz * EMA_OLD + sv.z * EMA_NEW;
            ns.w = dw * dw * EMA_OLD + sv.w * EMA_NEW;
            om[i] = nm;
            os[i] = ns;
        }
    } else {
        for (int i = t; i < KDIM / 4; i += 256) {
            om[i] = mp[i];
            os[i] = sp[i];
        }
    }
}

extern "C" void kernel_launch(void* const* d_in, const int* in_sizes, int n_in,
                              void* d_out, int out_size, void* d_ws,
                              size_t ws_size, hipStream_t stream) {
    const float* y  = (const float*)d_in[0];
    const float* m  = (const float*)d_in[1];
    const float* sd = (const float*)d_in[2];
    float* out = (float*)d_out;

    char* ws = (char*)d_ws;
    int* winner = (int*)(ws + WS_WINNER_OFF);
    float* yy   = (float*)(ws + WS_YY_OFF);
    float* mm   = (float*)(ws + WS_MM_OFF);
    short* pws  = (short*)(ws + WS_P_OFF);
    ushortT* yhi = (ushortT*)(ws + WS_YHI_OFF);
    ushortT* mhi = (ushortT*)(ws + WS_MHI_OFF);

    convert_sumsq<<<B_ROWS + N_CLUST, 256, 0, stream>>>(
        y, m, yhi, mhi, yy, mm, winner);

    screen_gemm<<<(B_ROWS / 128) * (N_CLUST / 128) * 4, 256, 0, stream>>>(
        yhi, mhi, pws);

    rescreen<<<B_ROWS / 4, 256, 0, stream>>>(pws, y, m, yy, mm, winner);

    write_out<<<N_CLUST, 256, 0, stream>>>(y, m, sd, winner, out);
}

// Round 6
// 214.126 us; speedup vs baseline: 1.0394x; 1.0061x over previous
//
#include <hip/hip_runtime.h>

#define B_ROWS 4096
#define N_CLUST 1024
#define KDIM 4096
#define NKT 32          // source k-tiles of 128 halfs
#define NSTEP 32        // BK=64 steps per block (split-K x2: 16 kt x 2)

#define EMA_OLD 0.01f
#define EMA_NEW 0.99f
#define MARGIN 2.0f     // screen error: ~0.27 f16 + 0.0625 i16 quant << 2.0
#define PSCALE 16.0f    // i16 partial quantization scale
#define PLANE ((size_t)B_ROWS * N_CLUST)

typedef unsigned short ushortT;
typedef _Float16 half8 __attribute__((ext_vector_type(8)));
typedef short short8v __attribute__((ext_vector_type(8)));
typedef float f32x16 __attribute__((ext_vector_type(16)));

// ---------------- workspace layout (bytes) ----------------
#define WS_WINNER_OFF 0                  // i32[1024], init by convert_sumsq
#define WS_YY_OFF     20480              // f32[4096]
#define WS_MM_OFF     36864              // f32[1024]
#define WS_P_OFF      65536              // i16[2][4096][1024] = 2 x 8 MiB
#define WS_YHI_OFF    (WS_P_OFF + 33554432)      // (upper 16 MB of P unused)
#define WS_MHI_OFF    (WS_YHI_OFF + 33554432)    // 8.4 MB
#define WS_END        (WS_MHI_OFF + 8388608)     // ~75 MB

// ---------------- fused f16-hi convert + row sum-of-squares ----------------
// Tiled layout: block (rb, kt) of 64 rows x 128 halfs contiguous (16 KB).
// Within a row (16 chunks of 16B), logical chunk c stored at p = c ^ (r&15).
// m-branch blocks also init winner[row] = -1 (replaces the memset node).
__global__ __launch_bounds__(256) void convert_sumsq(
    const float* __restrict__ ysrc, const float* __restrict__ msrc,
    ushortT* __restrict__ yhi, ushortT* __restrict__ mhi,
    float* __restrict__ yy, float* __restrict__ mm,
    int* __restrict__ winner) {
    const int blk = blockIdx.x;
    const float* src;
    ushortT* hi;
    float* out;
    int row;
    if (blk < B_ROWS) {
        src = ysrc; hi = yhi; out = yy + blk; row = blk;
    } else {
        row = blk - B_ROWS;
        src = msrc; hi = mhi; out = mm + row;
        if (threadIdx.x == 0) winner[row] = -1;   // fused memset
    }
    const int r = row & 63, rb = row >> 6;
    const int t = threadIdx.x;
    float s = 0.f;
#pragma unroll
    for (int h = 0; h < 2; ++h) {
        int ci = h * 256 + t;        // physical chunk in row [0,512)
        int kt = ci >> 4, p = ci & 15;
        int c = p ^ (r & 15);
        const float* sp = src + ((size_t)row << 12) + kt * 128 + c * 8;
        float4 v0 = *(const float4*)sp;
        float4 v1 = *(const float4*)(sp + 4);
        float vv[8] = {v0.x, v0.y, v0.z, v0.w, v1.x, v1.y, v1.z, v1.w};
        half8 hv;
#pragma unroll
        for (int i = 0; i < 8; ++i) {
            hv[i] = (_Float16)vv[i];
            s += vv[i] * vv[i];
        }
        size_t off = (((size_t)rb * NKT + kt) * 64 + r) * 128 + p * 8;
        *(half8*)(hi + off) = hv;
    }
    for (int off = 32; off > 0; off >>= 1) s += __shfl_down(s, off, 64);
    __shared__ float red[4];
    if ((t & 63) == 0) red[t >> 6] = s;
    __syncthreads();
    if (t == 0) out[0] = red[0] + red[1] + red[2] + red[3];
}

// ---------------- screen GEMM: partials of -2*Yhi@Mhi^T ------------------
__device__ __forceinline__ void gload_lds16(const void* g, void* l) {
    __builtin_amdgcn_global_load_lds(
        (const __attribute__((address_space(1))) unsigned int*)g,
        (__attribute__((address_space(3))) unsigned int*)l, 16, 0, 0);
}

// Pair-interleaved LDS layout (BK=64, conflict-free — v5, measured 0):
// phys_byte(r, c) = (r>>1)*256 + ((((r&1)<<3)|c) ^ ((r>>1)&15))*16.
// Among 32 lanes exactly 2 share a 16B slot -> 2-way = free.
__device__ __forceinline__ half8 ldfrag_pair(const ushortT* s, int r, int c) {
    int q = r >> 1;
    int sl = ((((r & 1) << 3) | c) ^ (q & 15));
    return *(const half8*)(s + q * 128 + sl * 8);
}

// v7: v5's conflict-free layout + v4's counted-vmcnt double-buffer (T3+T4).
// 128x128 block tile, 4 waves each 64x64 (1 KB LDS read per MFMA). BK=64,
// DOUBLE-buffered 2x32 KB = 64 KB -> 2 blocks/CU. Split-K x2, grid 512.
// Per step: issue next tile's 8 global_load_lds, s_waitcnt vmcnt(8) (only
// current tile drained; prefetch stays in flight across the barrier and
// hides under 16 MFMA + co-resident block), barrier, 16 ds_read + 16 MFMA
// (setprio-wrapped, T5), barrier. Output: per-K-half partial of -2*acc as
// i16 at scale 16 (|partial*16| <= ~12k << 32767; quant err 2/32 << MARGIN).
__global__ __launch_bounds__(256, 2) void screen_gemm(
    const ushortT* __restrict__ Ah, const ushortT* __restrict__ Bh,
    short* __restrict__ pws) {
    __shared__ __align__(16) ushortT sA[2][128 * 64];   // 2 x 16 KB
    __shared__ __align__(16) ushortT sB[2][128 * 64];   // 2 x 16 KB

    const int t = threadIdx.x, w = t >> 6, l = t & 63;
    const int by = blockIdx.x & 7;            // col panel -> XCD pinned
    const int kh = (blockIdx.x >> 3) & 1;     // K half
    const int bx = blockIdx.x >> 4;           // row tile 0..31
    const int row0 = bx * 128, col0 = by * 128;
    const int wr = (w >> 1) * 64, wc = (w & 1) * 64;   // wave 64x64 tile
    const int m0 = l & 31, hsel = l >> 5;

    // Per-lane source offsets for the 4 staged chunks (ks flips byte bit 7).
    int laneoff[4];
#pragma unroll
    for (int j = 0; j < 4; ++j) {
        int g = w * 4 + j;
        int q = g * 4 + (l >> 4);
        int u = (l & 15) ^ (q & 15);
        int rr = 2 * q + (u >> 3);
        int R = rr & 63;
        int hi3 = (R >> 3) & 1;
        laneoff[j] = R * 256 + ((((hi3 << 3) | ((u & 7) ^ (R & 7)))) << 4);
    }

    f32x16 acc[2][2];
#pragma unroll
    for (int i = 0; i < 2; ++i)
#pragma unroll
        for (int j = 0; j < 2; ++j)
#pragma unroll
            for (int r = 0; r < 16; ++r) acc[i][j][r] = 0.f;

    const int ra0 = wr + m0, ra1 = wr + 32 + m0;
    const int rb0 = wc + m0, rb1 = wc + 32 + m0;

#define STAGE(buf, step)                                                      \
    {                                                                         \
        const int kt_ = kh * (NKT / 2) + ((step) >> 1);                       \
        const int ks_ = (step) & 1;                                           \
        _Pragma("unroll")                                                     \
        for (int j = 0; j < 4; ++j) {                                         \
            const int g = w * 4 + j;                                          \
            const int lo = laneoff[j] ^ (ks_ << 7);                           \
            const size_t tbA =                                                \
                ((size_t)((2 * bx + (g >> 3)) * NKT + kt_) << 14);            \
            const size_t tbB =                                                \
                ((size_t)((2 * by + (g >> 3)) * NKT + kt_) << 14);            \
            gload_lds16((const char*)Ah + tbA + lo,                           \
                        (char*)&sA[buf][0] + g * 1024);                       \
            gload_lds16((const char*)Bh + tbB + lo,                           \
                        (char*)&sB[buf][0] + g * 1024);                       \
        }                                                                     \
    }

    STAGE(0, 0);                       // prologue: 8 loads in flight

#pragma unroll 2
    for (int i = 0; i < NSTEP; ++i) {
        const int buf = i & 1;
        if (i + 1 < NSTEP) {
            STAGE(buf ^ 1, i + 1);                        // 16 in flight
            asm volatile("s_waitcnt vmcnt(8)" ::: "memory");  // drain step i only
        } else {
            asm volatile("s_waitcnt vmcnt(0)" ::: "memory");
        }
        __builtin_amdgcn_s_barrier();  // step i's tile visible to all waves

        const ushortT* tA = &sA[buf][0];
        const ushortT* tB = &sB[buf][0];
        __builtin_amdgcn_s_setprio(1);
#pragma unroll
        for (int kk = 0; kk < 4; ++kk) {
            int c = kk * 2 + hsel;
            half8 a0 = ldfrag_pair(tA, ra0, c);
            half8 a1 = ldfrag_pair(tA, ra1, c);
            half8 b0 = ldfrag_pair(tB, rb0, c);
            half8 b1 = ldfrag_pair(tB, rb1, c);
            acc[0][0] = __builtin_amdgcn_mfma_f32_32x32x16_f16(a0, b0, acc[0][0], 0, 0, 0);
            acc[0][1] = __builtin_amdgcn_mfma_f32_32x32x16_f16(a0, b1, acc[0][1], 0, 0, 0);
            acc[1][0] = __builtin_amdgcn_mfma_f32_32x32x16_f16(a1, b0, acc[1][0], 0, 0, 0);
            acc[1][1] = __builtin_amdgcn_mfma_f32_32x32x16_f16(a1, b1, acc[1][1], 0, 0, 0);
        }
        __builtin_amdgcn_s_setprio(0);
        asm volatile("" ::: "memory"); // keep ds_reads above the barrier
        __builtin_amdgcn_s_barrier();  // all reads of buf done before re-stage
    }
#undef STAGE

    // Store i16 partial: round(-2*acc*16).
    short* pk = pws + (size_t)kh * PLANE;
#pragma unroll
    for (int i = 0; i < 2; ++i)
#pragma unroll
        for (int j = 0; j < 2; ++j) {
            const int gcol = col0 + wc + j * 32 + m0;
#pragma unroll
            for (int r = 0; r < 16; ++r) {
                int ri = (r & 3) + 8 * (r >> 2) + 4 * hsel;
                int grow = row0 + wr + i * 32 + ri;
                float q = fmaxf(fminf(acc[i][j][r] * (-2.0f * PSCALE),
                                      32767.f), -32767.f);
                pk[(size_t)grow * N_CLUST + gcol] = (short)__float2int_rn(q);
            }
        }
}

// ---------------- rescreen: exact argmin per row + winner scatter ---------
// Vectorized (v6). One wave per row; lane l owns cols [l*16, l*16+16).
// Loads: 2 planes x 2 short8 (16B) + 4 float4 mm. Per-lane (min1, argmin,
// min2), 6-step shfl_xor merge (disjoint col sets -> exact). Fast path:
// min2-min1 > MARGIN. Rare exact path: fp64 dots, lowest-j tiebreak.
__global__ __launch_bounds__(256) void rescreen(
    const short* __restrict__ pws, const float* __restrict__ ysrc,
    const float* __restrict__ msrc, const float* __restrict__ yy,
    const float* __restrict__ mm, int* __restrict__ winner) {
    const int row = blockIdx.x * 4 + (threadIdx.x >> 6);
    const int l = threadIdx.x & 63;
    const size_t rb = (size_t)row * N_CLUST;

    // gather 16-col strip summed over 2 planes
    int sacc[16];
#pragma unroll
    for (int q = 0; q < 16; ++q) sacc[q] = 0;
    const short* base = pws + rb + l * 16;
#pragma unroll
    for (int pl = 0; pl < 2; ++pl) {
        const short8v* sp = (const short8v*)(base + pl * PLANE);
        short8v x0 = sp[0], x1 = sp[1];
#pragma unroll
        for (int e = 0; e < 8; ++e) {
            sacc[e] += (int)x0[e];
            sacc[8 + e] += (int)x1[e];
        }
    }
    float v[16];
    const float4* mmv = (const float4*)(mm + l * 16);
#pragma unroll
    for (int h = 0; h < 4; ++h) {
        float4 mv = mmv[h];
        v[h * 4 + 0] = mv.x + (float)sacc[h * 4 + 0] * (1.0f / PSCALE);
        v[h * 4 + 1] = mv.y + (float)sacc[h * 4 + 1] * (1.0f / PSCALE);
        v[h * 4 + 2] = mv.z + (float)sacc[h * 4 + 2] * (1.0f / PSCALE);
        v[h * 4 + 3] = mv.w + (float)sacc[h * 4 + 3] * (1.0f / PSCALE);
    }

    // per-lane min1/argmin/min2 (ascending q: strict < keeps lowest col)
    float m1 = v[0], m2 = 3.0e38f;
    int a1 = l * 16;
#pragma unroll
    for (int q = 1; q < 16; ++q) {
        float x = v[q];
        if (x < m1) { m2 = m1; m1 = x; a1 = l * 16 + q; }
        else m2 = fminf(m2, x);
    }
    // cross-lane merge (disjoint col sets)
#pragma unroll
    for (int s = 1; s <= 32; s <<= 1) {
        float o1 = __shfl_xor(m1, s, 64);
        int ob = __shfl_xor(a1, s, 64);
        float o2 = __shfl_xor(m2, s, 64);
        if (o1 < m1 || (o1 == m1 && ob < a1)) {
            m2 = fminf(o2, m1); m1 = o1; a1 = ob;
        } else {
            m2 = fminf(m2, o1);
        }
    }

    int zj;
    if (m2 - m1 > MARGIN) {
        zj = a1;                      // unique screen winner
    } else {
        const float thr = m1 + MARGIN;
        double bestd = 1e300;
        int bestj = 0x7FFFFFFF;
        const float yyr = yy[row];
        const float4* yp = (const float4*)(ysrc + (size_t)row * KDIM);
        for (int q = 0; q < 16; ++q) {
            unsigned long long mask = __ballot(v[q] <= thr);
            while (mask) {
                int lb = __ffsll((unsigned long long)mask) - 1;
                mask &= mask - 1;
                int j = lb * 16 + q;
                const float4* mp = (const float4*)(msrc + (size_t)j * KDIM);
                double acc = 0.0;
#pragma unroll
                for (int tt = 0; tt < 16; ++tt) {
                    float4 a = yp[l + 64 * tt];
                    float4 b = mp[l + 64 * tt];
                    acc += (double)a.x * b.x + (double)a.y * b.y +
                           (double)a.z * b.z + (double)a.w * b.w;
                }
#pragma unroll
                for (int s = 1; s <= 32; s <<= 1)
                    acc += __shfl_xor(acc, s, 64);
                double d2x = (double)yyr - 2.0 * acc + (double)mm[j];
                if (d2x < bestd || (d2x == bestd && j < bestj)) {
                    bestd = d2x; bestj = j;   // lowest j wins ties
                }
            }
        }
        zj = bestj;
    }
    if (l == 0) atomicMax(&winner[zj], row);   // fused pick_winner
}

// ---------------- output ----------------
__global__ __launch_bounds__(256) void write_out(
    const float* __restrict__ y, const float* __restrict__ m,
    const float* __restrict__ sd, const int* __restrict__ winner,
    float* __restrict__ out) {
    const int idx = blockIdx.x;
    const int t = threadIdx.x;
    const int w = winner[idx];
    const float4* mp = (const float4*)(m + (size_t)idx * KDIM);
    const float4* sp = (const float4*)(sd + (size_t)idx * KDIM);
    float4* om = (float4*)(out + (size_t)idx * KDIM);
    float4* os = (float4*)(out + (size_t)(N_CLUST + idx) * KDIM);
    if (w >= 0) {
        const float4* yp = (const float4*)(y + (size_t)w * KDIM);
        for (int i = t; i < KDIM / 4; i += 256) {
            float4 mv = mp[i], yv = yp[i], sv = sp[i];
            float4 nm, ns;
            nm.x = mv.x * EMA_OLD + yv.x * EMA_NEW;
            nm.y = mv.y * EMA_OLD + yv.y * EMA_NEW;
            nm.z = mv.z * EMA_OLD + yv.z * EMA_NEW;
            nm.w = mv.w * EMA_OLD + yv.w * EMA_NEW;
            float dx = nm.x - yv.x, dy = nm.y - yv.y;
            float dz = nm.z - yv.z, dw = nm.w - yv.w;
            ns.x = dx * dx * EMA_OLD + sv.x * EMA_NEW;
            ns.y = dy * dy * EMA_OLD + sv.y * EMA_NEW;
            ns.z = dz * dz * EMA_OLD + sv.z * EMA_NEW;
            ns.w = dw * dw * EMA_OLD + sv.w * EMA_NEW;
            om[i] = nm;
            os[i] = ns;
        }
    } else {
        for (int i = t; i < KDIM / 4; i += 256) {
            om[i] = mp[i];
            os[i] = sp[i];
        }
    }
}

extern "C" void kernel_launch(void* const* d_in, const int* in_sizes, int n_in,
                              void* d_out, int out_size, void* d_ws,
                              size_t ws_size, hipStream_t stream) {
    const float* y  = (const float*)d_in[0];
    const float* m  = (const float*)d_in[1];
    const float* sd = (const float*)d_in[2];
    float* out = (float*)d_out;

    char* ws = (char*)d_ws;
    int* winner = (int*)(ws + WS_WINNER_OFF);
    float* yy   = (float*)(ws + WS_YY_OFF);
    float* mm   = (float*)(ws + WS_MM_OFF);
    short* pws  = (short*)(ws + WS_P_OFF);
    ushortT* yhi = (ushortT*)(ws + WS_YHI_OFF);
    ushortT* mhi = (ushortT*)(ws + WS_MHI_OFF);

    convert_sumsq<<<B_ROWS + N_CLUST, 256, 0, stream>>>(
        y, m, yhi, mhi, yy, mm, winner);

    screen_gemm<<<(B_ROWS / 128) * (N_CLUST / 128) * 2, 256, 0, stream>>>(
        yhi, mhi, pws);

    rescreen<<<B_ROWS / 4, 256, 0, stream>>>(pws, y, m, yy, mm, winner);

    write_out<<<N_CLUST, 256, 0, stream>>>(y, m, sd, winner, out);
}